// Round 14
// baseline (320.388 us; speedup 1.0000x reference)
//
#include <hip/hip_runtime.h>

#define EPS 1e-5f
#define SLOPE 0.2f
#define MAXK 512
#define SEGCAP 12288   // fixed segment stride; mean fill 8192
#define PBATCH 8192    // per partition block (1024 threads, 8 edges/thread)

__device__ __forceinline__ float leaky(float z) {
    return fmaxf(z, 0.f) + SLOPE * fminf(z, 0.f);
}
__device__ __forceinline__ ushort f2bf(float f) {
    unsigned u = __float_as_uint(f);
    u += 0x7FFFu + ((u >> 16) & 1u);
    return (ushort)(u >> 16);
}
__device__ __forceinline__ float bf2f(ushort b) {
    return __uint_as_float(((unsigned)b) << 16);
}

// -- fused stage 1: [blocks 0..EB): edge partition] ∥ [blocks EB..: prep1] --
__global__ __launch_bounds__(1024) void fused1(
    const int* __restrict__ ei, int E, int K, int* __restrict__ segcnt,
    unsigned* __restrict__ part,
    const float* __restrict__ x, const float* __restrict__ W1,
    const float* __restrict__ as1, const float* __restrict__ ad1,
    ushort* __restrict__ h1b, float* __restrict__ al_s, float* __restrict__ al_d,
    int N, int EB) {
    __shared__ float smem[4096 + 64 * 68];   // Ws | xs
    int t = threadIdx.x;
    if ((int)blockIdx.x < EB) {
        // ---------------- partition branch ----------------
        int* h   = (int*)smem;
        int* gp  = h + 512;
        int* run = h + 1024;
        for (int i = t; i < K; i += 1024) { h[i] = 0; run[i] = 0; }
        __syncthreads();
        int base = blockIdx.x * PBATCH;
        int sv[PBATCH / 1024], dv[PBATCH / 1024];
#pragma unroll
        for (int j = 0; j < PBATCH / 1024; j++) {
            int e = base + j * 1024 + t;
            sv[j] = (e < E) ? ei[e] : -1;
            dv[j] = (e < E) ? ei[E + e] : -1;
            if (dv[j] >= 0) atomicAdd(&h[dv[j] >> 8], 1);
        }
        __syncthreads();
        for (int i = t; i < K; i += 1024)
            gp[i] = h[i] ? atomicAdd(&segcnt[i * 16], h[i]) : 0;
        __syncthreads();
#pragma unroll
        for (int j = 0; j < PBATCH / 1024; j++) {
            if (dv[j] >= 0) {
                int b = dv[j] >> 8;
                int p = atomicAdd(&run[b], 1) + gp[b];
                if (p < SEGCAP)
                    part[(size_t)b * SEGCAP + p] =
                        ((unsigned)sv[j] << 8) | (unsigned)(dv[j] & 255);
            }
        }
        return;
    }
    // ---------------- prep1 branch: 64 rows/block ----------------
    float* Ws = smem;
    float (*xs)[68] = (float(*)[68])(smem + 4096);
    for (int i = t; i < 4096; i += 1024) Ws[i] = W1[i];
    int base = (blockIdx.x - EB) * 64;
    {
        int rr = t >> 4, kk = t & 15;
        int gr = base + rr;
        float4 vx = (gr < N) ? ((const float4*)x)[(size_t)gr * 16 + kk]
                             : make_float4(0.f, 0.f, 0.f, 0.f);
        *(float4*)&xs[rr][kk * 4] = vx;
    }
    __syncthreads();
    int wv = t >> 6, c = t & 63;
    int r0 = base + wv * 4;
    float acc0 = 0.f, acc1 = 0.f, acc2 = 0.f, acc3 = 0.f;
#pragma unroll
    for (int k = 0; k < 64; k += 4) {
        float4 x0 = *(const float4*)&xs[wv * 4 + 0][k];
        float4 x1 = *(const float4*)&xs[wv * 4 + 1][k];
        float4 x2 = *(const float4*)&xs[wv * 4 + 2][k];
        float4 x3 = *(const float4*)&xs[wv * 4 + 3][k];
        float w0 = Ws[(k + 0) * 64 + c];
        float w1 = Ws[(k + 1) * 64 + c];
        float w2 = Ws[(k + 2) * 64 + c];
        float w3 = Ws[(k + 3) * 64 + c];
        acc0 = fmaf(x0.x, w0, acc0); acc1 = fmaf(x1.x, w0, acc1);
        acc2 = fmaf(x2.x, w0, acc2); acc3 = fmaf(x3.x, w0, acc3);
        acc0 = fmaf(x0.y, w1, acc0); acc1 = fmaf(x1.y, w1, acc1);
        acc2 = fmaf(x2.y, w1, acc2); acc3 = fmaf(x3.y, w1, acc3);
        acc0 = fmaf(x0.z, w2, acc0); acc1 = fmaf(x1.z, w2, acc1);
        acc2 = fmaf(x2.z, w2, acc2); acc3 = fmaf(x3.z, w2, acc3);
        acc0 = fmaf(x0.w, w3, acc0); acc1 = fmaf(x1.w, w3, acc1);
        acc2 = fmaf(x2.w, w3, acc2); acc3 = fmaf(x3.w, w3, acc3);
    }
    int head = c >> 5, cc = c & 31;
    float asc = as1[head * 32 + cc], adc = ad1[head * 32 + cc];
    float vs0 = acc0 * asc, vd0 = acc0 * adc;
    float vs1 = acc1 * asc, vd1 = acc1 * adc;
    float vs2 = acc2 * asc, vd2 = acc2 * adc;
    float vs3 = acc3 * asc, vd3 = acc3 * adc;
#pragma unroll
    for (int off = 1; off < 32; off <<= 1) {
        vs0 += __shfl_xor(vs0, off); vd0 += __shfl_xor(vd0, off);
        vs1 += __shfl_xor(vs1, off); vd1 += __shfl_xor(vd1, off);
        vs2 += __shfl_xor(vs2, off); vd2 += __shfl_xor(vd2, off);
        vs3 += __shfl_xor(vs3, off); vd3 += __shfl_xor(vd3, off);
    }
    if (r0 + 0 < N) h1b[(size_t)(r0 + 0) * 64 + c] = f2bf(acc0);
    if (r0 + 1 < N) h1b[(size_t)(r0 + 1) * 64 + c] = f2bf(acc1);
    if (r0 + 2 < N) h1b[(size_t)(r0 + 2) * 64 + c] = f2bf(acc2);
    if (r0 + 3 < N) h1b[(size_t)(r0 + 3) * 64 + c] = f2bf(acc3);
    if (cc == 0) {
        if (r0 + 0 < N) { al_s[(r0 + 0) * 2 + head] = vs0; al_d[(r0 + 0) * 2 + head] = vd0; }
        if (r0 + 1 < N) { al_s[(r0 + 1) * 2 + head] = vs1; al_d[(r0 + 1) * 2 + head] = vd1; }
        if (r0 + 2 < N) { al_s[(r0 + 2) * 2 + head] = vs2; al_d[(r0 + 2) * 2 + head] = vd2; }
        if (r0 + 3 < N) { al_s[(r0 + 3) * 2 + head] = vs3; al_d[(r0 + 3) * 2 + head] = vd3; }
    }
}

// -- stage 2: per-segment LDS counting sort over 12-bit key (dst8, src>>13)
__global__ __launch_bounds__(256) void sortseg(
    const int* __restrict__ segcnt, int N,
    unsigned* __restrict__ part, int* __restrict__ nodeofs, int* __restrict__ cnt,
    int* __restrict__ perm) {
    __shared__ int h2[4096];
    __shared__ int sc[256];
    __shared__ int ex[256];
    __shared__ unsigned outb[SEGCAP];
    int b = blockIdx.x, t = threadIdx.x;
    size_t base = (size_t)b * SEGCAP;
    int sz = min(segcnt[b * 16], SEGCAP);
    for (int i = t; i < 4096; i += 256) h2[i] = 0;
    __syncthreads();
    for (int i = t; i < sz; i += 256) {
        unsigned code = part[base + i];
        int key = ((code & 255) << 4) | ((code >> 21) & 15);
        atomicAdd(&h2[key], 1);
    }
    __syncthreads();
    int loc[16];
    int v = 0;
#pragma unroll
    for (int i = 0; i < 16; i++) { loc[i] = h2[t * 16 + i]; v += loc[i]; }
    sc[t] = v;
    __syncthreads();
    for (int off = 1; off < 256; off <<= 1) {
        int x = (t >= off) ? sc[t - off] : 0;
        __syncthreads();
        sc[t] += x;
        __syncthreads();
    }
    int exv = sc[t] - v;
    {
        int run = exv;
#pragma unroll
        for (int i = 0; i < 16; i++) { h2[t * 16 + i] = run; run += loc[i]; }
    }
    int n = b * 256 + t;
    if (n < N) { cnt[n] = v; nodeofs[n] = (int)(base + exv); }
    __syncthreads();
    for (int i = t; i < sz; i += 256) {
        unsigned code = part[base + i];
        int key = ((code & 255) << 4) | ((code >> 21) & 15);
        int p = atomicAdd(&h2[key], 1);
        outb[p] = code >> 8;          // src
    }
    __syncthreads();
    for (int i = t; i < sz; i += 256) part[base + i] = outb[i];
    // ---- segment-local degree sort -> perm ----
    __syncthreads();
    h2[t] = 0;
    __syncthreads();
    int dbin = min(v, 255);
    if (n < N) atomicAdd(&h2[dbin], 1);
    __syncthreads();
    int hv = h2[t];
    sc[t] = hv;
    __syncthreads();
    for (int off = 1; off < 256; off <<= 1) {
        int x = (t >= off) ? sc[t - off] : 0;
        __syncthreads();
        sc[t] += x;
        __syncthreads();
    }
    ex[t] = sc[t] - hv;
    __syncthreads();
    if (n < N) {
        int r = atomicAdd(&ex[dbin], 1);
        perm[b * 256 + r] = n;
    }
}

// -- layer1 aggregation: lane-cooperative 16-edge batches + LN + ELU --------
__global__ __launch_bounds__(256) void aggB1(
    const ushort* __restrict__ h1b, const float* __restrict__ als,
    const float* __restrict__ ald, const int* __restrict__ nodeofs,
    const int* __restrict__ cnt, const unsigned* __restrict__ csr,
    const int* __restrict__ perm,
    const float* __restrict__ b1, const float* __restrict__ g1,
    const float* __restrict__ bb1, ushort* __restrict__ h1out, int N) {
    int lane = threadIdx.x & 63;
    int grp = lane >> 4, q = lane & 15;
    int gbase = grp << 4;
    int idx = blockIdx.x * 16 + (threadIdx.x >> 6) * 4 + grp;
    bool valid = idx < N;
    int nc = perm[min(idx, N - 1)];
    int head = q >> 3;
    const float2* als2 = (const float2*)als;
    const float2* ald2 = (const float2*)ald;
    float2 adv = ald2[nc], asv = als2[nc];
    float ad0 = adv.x, ad1v = adv.y;
    float wsf = __expf(leaky((head ? asv.y : asv.x) + (head ? ad1v : ad0)));
    const ushort4* h4 = (const ushort4*)h1b;
    ushort4 hs = h4[(unsigned)nc * 16 + q];
    float a0 = wsf * bf2f(hs.x), a1 = wsf * bf2f(hs.y);
    float a2 = wsf * bf2f(hs.z), a3 = wsf * bf2f(hs.w);
    float l0p = 0.f, l1p = 0.f;
    int ofs = valid ? nodeofs[nc] : 0;
    int deg = valid ? cnt[nc] : 0;
    int degm1 = max(deg - 1, 0);
    int degmax = deg;              // deg uniform within 16-lane group
    degmax = max(degmax, __shfl_xor(degmax, 16));
    degmax = max(degmax, __shfl_xor(degmax, 32));
    for (int eb = 0; eb < degmax; eb += 16) {
        int j = ofs + min(eb + q, degm1);
        int sq = min((int)csr[j], N - 1);
        float2 av = als2[sq];
        float z0 = leaky(av.x + ad0);
        float z1 = leaky(av.y + ad1v);
        bool ev = (eb + q < deg);
        float w0q = ev ? __expf(z0) : 0.f;
        float w1q = ev ? __expf(z1) : 0.f;
        l0p += w0q;
        l1p += w1q;
#pragma unroll
        for (int jj = 0; jj < 16; jj++) {
            int s = __shfl(sq, gbase + jj);
            float w0 = __shfl(w0q, gbase + jj);
            float w1 = __shfl(w1q, gbase + jj);
            float w = head ? w1 : w0;
            ushort4 hv = h4[(unsigned)s * 16 + q];
            a0 = fmaf(w, bf2f(hv.x), a0);
            a1 = fmaf(w, bf2f(hv.y), a1);
            a2 = fmaf(w, bf2f(hv.z), a2);
            a3 = fmaf(w, bf2f(hv.w), a3);
        }
    }
#pragma unroll
    for (int off = 1; off < 16; off <<= 1) {
        l0p += __shfl_xor(l0p, off);
        l1p += __shfl_xor(l1p, off);
    }
    if (!valid) return;
    float l = (head ? l1p : l0p) + wsf;
    float inv = 1.f / l;
    float4 bv = ((const float4*)b1)[q];
    float v0 = a0 * inv + bv.x, v1 = a1 * inv + bv.y;
    float v2 = a2 * inv + bv.z, v3 = a3 * inv + bv.w;
    float s1 = v0 + v1 + v2 + v3;
#pragma unroll
    for (int off = 1; off < 16; off <<= 1) s1 += __shfl_xor(s1, off);
    float mu = s1 * (1.f / 64.f);
    float d0 = v0 - mu, d1 = v1 - mu, d2 = v2 - mu, d3 = v3 - mu;
    float s2v = d0 * d0 + d1 * d1 + d2 * d2 + d3 * d3;
#pragma unroll
    for (int off = 1; off < 16; off <<= 1) s2v += __shfl_xor(s2v, off);
    float rs = rsqrtf(s2v * (1.f / 64.f) + EPS);
    float4 gv = ((const float4*)g1)[q];
    float4 bbv = ((const float4*)bb1)[q];
    float y0 = d0 * rs * gv.x + bbv.x;
    float y1 = d1 * rs * gv.y + bbv.y;
    float y2 = d2 * rs * gv.z + bbv.z;
    float y3 = d3 * rs * gv.w + bbv.w;
    y0 = (y0 > 0.f) ? y0 : (__expf(y0) - 1.f);
    y1 = (y1 > 0.f) ? y1 : (__expf(y1) - 1.f);
    y2 = (y2 > 0.f) ? y2 : (__expf(y2) - 1.f);
    y3 = (y3 > 0.f) ? y3 : (__expf(y3) - 1.f);
    ((ushort4*)h1out)[(unsigned)nc * 16 + q] =
        make_ushort4(f2bf(y0), f2bf(y1), f2bf(y2), f2bf(y3));
}

// -- layer2 prep: h2 = h1out(bf16) @ W2 (bf16 out), 4 rows/lane tile --------
__global__ __launch_bounds__(256) void prep2(
    const ushort* __restrict__ h1ob, const float* __restrict__ W2,
    const float* __restrict__ as2, const float* __restrict__ ad2,
    ushort* __restrict__ h2b, float* __restrict__ al_s, float* __restrict__ al_d, int N) {
    __shared__ float Ws[64 * 32];
    __shared__ float xs[32][68];
    int t = threadIdx.x;
    for (int i = t; i < 64 * 32; i += 256) Ws[i] = W2[i];
    int base = blockIdx.x * 32;
    const ushort4* hv4 = (const ushort4*)h1ob;
    for (int i = t; i < 512; i += 256) {
        int rr = i >> 4, kk = i & 15;
        int gr = base + rr;
        ushort4 u = (gr < N) ? hv4[(unsigned)gr * 16 + kk] : make_ushort4(0, 0, 0, 0);
        xs[rr][kk * 4 + 0] = bf2f(u.x);
        xs[rr][kk * 4 + 1] = bf2f(u.y);
        xs[rr][kk * 4 + 2] = bf2f(u.z);
        xs[rr][kk * 4 + 3] = bf2f(u.w);
    }
    __syncthreads();
    int wv = t >> 6;
    int lane = t & 63;
    int half = lane >> 5, c = lane & 31;
    int rbase = wv * 8 + half * 4;
    int r0 = base + rbase;
    float acc0 = 0.f, acc1 = 0.f, acc2 = 0.f, acc3 = 0.f;
#pragma unroll
    for (int k = 0; k < 64; k += 4) {
        float4 x0 = *(const float4*)&xs[rbase + 0][k];
        float4 x1 = *(const float4*)&xs[rbase + 1][k];
        float4 x2 = *(const float4*)&xs[rbase + 2][k];
        float4 x3 = *(const float4*)&xs[rbase + 3][k];
        float w0 = Ws[(k + 0) * 32 + c];
        float w1 = Ws[(k + 1) * 32 + c];
        float w2 = Ws[(k + 2) * 32 + c];
        float w3 = Ws[(k + 3) * 32 + c];
        acc0 = fmaf(x0.x, w0, acc0); acc1 = fmaf(x1.x, w0, acc1);
        acc2 = fmaf(x2.x, w0, acc2); acc3 = fmaf(x3.x, w0, acc3);
        acc0 = fmaf(x0.y, w1, acc0); acc1 = fmaf(x1.y, w1, acc1);
        acc2 = fmaf(x2.y, w1, acc2); acc3 = fmaf(x3.y, w1, acc3);
        acc0 = fmaf(x0.z, w2, acc0); acc1 = fmaf(x1.z, w2, acc1);
        acc2 = fmaf(x2.z, w2, acc2); acc3 = fmaf(x3.z, w2, acc3);
        acc0 = fmaf(x0.w, w3, acc0); acc1 = fmaf(x1.w, w3, acc1);
        acc2 = fmaf(x2.w, w3, acc2); acc3 = fmaf(x3.w, w3, acc3);
    }
    float asc = as2[c], adc = ad2[c];
    float vs0 = acc0 * asc, vd0 = acc0 * adc;
    float vs1 = acc1 * asc, vd1 = acc1 * adc;
    float vs2 = acc2 * asc, vd2 = acc2 * adc;
    float vs3 = acc3 * asc, vd3 = acc3 * adc;
#pragma unroll
    for (int off = 1; off < 32; off <<= 1) {
        vs0 += __shfl_xor(vs0, off); vd0 += __shfl_xor(vd0, off);
        vs1 += __shfl_xor(vs1, off); vd1 += __shfl_xor(vd1, off);
        vs2 += __shfl_xor(vs2, off); vd2 += __shfl_xor(vd2, off);
        vs3 += __shfl_xor(vs3, off); vd3 += __shfl_xor(vd3, off);
    }
    if (r0 + 0 < N) h2b[(size_t)(r0 + 0) * 32 + c] = f2bf(acc0);
    if (r0 + 1 < N) h2b[(size_t)(r0 + 1) * 32 + c] = f2bf(acc1);
    if (r0 + 2 < N) h2b[(size_t)(r0 + 2) * 32 + c] = f2bf(acc2);
    if (r0 + 3 < N) h2b[(size_t)(r0 + 3) * 32 + c] = f2bf(acc3);
    if (c == 0) {
        if (r0 + 0 < N) { al_s[r0 + 0] = vs0; al_d[r0 + 0] = vd0; }
        if (r0 + 1 < N) { al_s[r0 + 1] = vs1; al_d[r0 + 1] = vd1; }
        if (r0 + 2 < N) { al_s[r0 + 2] = vs2; al_d[r0 + 2] = vd2; }
        if (r0 + 3 < N) { al_s[r0 + 3] = vs3; al_d[r0 + 3] = vd3; }
    }
}

// -- layer2 aggregation: 8-edge batches + bias + LN + ELU + out projection --
__global__ __launch_bounds__(256) void aggB2(
    const ushort* __restrict__ h2b, const float* __restrict__ als,
    const float* __restrict__ ald, const int* __restrict__ nodeofs,
    const int* __restrict__ cnt, const unsigned* __restrict__ csr,
    const int* __restrict__ perm,
    const float* __restrict__ b2, const float* __restrict__ g2,
    const float* __restrict__ bb2, const float* __restrict__ Wout,
    const float* __restrict__ bout, float* __restrict__ out, int N) {
    int lane = threadIdx.x & 63;
    int grp = lane >> 3, q = lane & 7;
    int gbase = grp << 3;
    int idx = blockIdx.x * 32 + (threadIdx.x >> 6) * 8 + grp;
    bool valid = idx < N;
    int nc = perm[min(idx, N - 1)];
    float myad = ald[nc];
    float wsf = __expf(leaky(als[nc] + myad));
    const ushort4* h4 = (const ushort4*)h2b;
    ushort4 hs = h4[(unsigned)nc * 8 + q];
    float a0 = wsf * bf2f(hs.x), a1 = wsf * bf2f(hs.y);
    float a2 = wsf * bf2f(hs.z), a3 = wsf * bf2f(hs.w);
    float lp = 0.f;
    int ofs = valid ? nodeofs[nc] : 0;
    int deg = valid ? cnt[nc] : 0;
    int degm1 = max(deg - 1, 0);
    int degmax = deg;              // uniform within 8-lane group
    degmax = max(degmax, __shfl_xor(degmax, 8));
    degmax = max(degmax, __shfl_xor(degmax, 16));
    degmax = max(degmax, __shfl_xor(degmax, 32));
    for (int eb = 0; eb < degmax; eb += 8) {
        int j = ofs + min(eb + q, degm1);
        int sq = min((int)csr[j], N - 1);
        float z = leaky(als[sq] + myad);
        float wq = (eb + q < deg) ? __expf(z) : 0.f;
        lp += wq;
#pragma unroll
        for (int jj = 0; jj < 8; jj++) {
            int s = __shfl(sq, gbase + jj);
            float w = __shfl(wq, gbase + jj);
            ushort4 hv = h4[(unsigned)s * 8 + q];
            a0 = fmaf(w, bf2f(hv.x), a0);
            a1 = fmaf(w, bf2f(hv.y), a1);
            a2 = fmaf(w, bf2f(hv.z), a2);
            a3 = fmaf(w, bf2f(hv.w), a3);
        }
    }
#pragma unroll
    for (int off = 1; off < 8; off <<= 1) lp += __shfl_xor(lp, off);
    if (!valid) return;
    float l = lp + wsf;
    float inv = 1.f / l;
    float4 bv = ((const float4*)b2)[q];
    float v0 = a0 * inv + bv.x, v1 = a1 * inv + bv.y;
    float v2 = a2 * inv + bv.z, v3 = a3 * inv + bv.w;
    float s1 = v0 + v1 + v2 + v3;
#pragma unroll
    for (int off = 1; off < 8; off <<= 1) s1 += __shfl_xor(s1, off);
    float mu = s1 * (1.f / 32.f);
    float d0 = v0 - mu, d1 = v1 - mu, d2 = v2 - mu, d3 = v3 - mu;
    float s2v = d0 * d0 + d1 * d1 + d2 * d2 + d3 * d3;
#pragma unroll
    for (int off = 1; off < 8; off <<= 1) s2v += __shfl_xor(s2v, off);
    float rs = rsqrtf(s2v * (1.f / 32.f) + EPS);
    float4 gv = ((const float4*)g2)[q];
    float4 bbv = ((const float4*)bb2)[q];
    float y0 = d0 * rs * gv.x + bbv.x;
    float y1 = d1 * rs * gv.y + bbv.y;
    float y2 = d2 * rs * gv.z + bbv.z;
    float y3 = d3 * rs * gv.w + bbv.w;
    y0 = (y0 > 0.f) ? y0 : (__expf(y0) - 1.f);
    y1 = (y1 > 0.f) ? y1 : (__expf(y1) - 1.f);
    y2 = (y2 > 0.f) ? y2 : (__expf(y2) - 1.f);
    y3 = (y3 > 0.f) ? y3 : (__expf(y3) - 1.f);
    float4 wo = ((const float4*)Wout)[q];
    float p = y0 * wo.x + y1 * wo.y + y2 * wo.z + y3 * wo.w;
#pragma unroll
    for (int off = 1; off < 8; off <<= 1) p += __shfl_xor(p, off);
    if (q == 0) out[nc] = p + bout[0];
}

extern "C" void kernel_launch(void* const* d_in, const int* in_sizes, int n_in,
                              void* d_out, int out_size, void* d_ws, size_t ws_size,
                              hipStream_t stream) {
    const float* x    = (const float*)d_in[0];
    const int*   ei   = (const int*)d_in[1];
    const float* W1   = (const float*)d_in[2];
    const float* as1  = (const float*)d_in[3];
    const float* ad1  = (const float*)d_in[4];
    const float* b1   = (const float*)d_in[5];
    const float* g1   = (const float*)d_in[6];
    const float* bb1  = (const float*)d_in[7];
    const float* W2   = (const float*)d_in[8];
    const float* as2  = (const float*)d_in[9];
    const float* ad2  = (const float*)d_in[10];
    const float* b2   = (const float*)d_in[11];
    const float* g2   = (const float*)d_in[12];
    const float* bb2  = (const float*)d_in[13];
    const float* Wout = (const float*)d_in[14];
    const float* bout = (const float*)d_in[15];
    float* out = (float*)d_out;

    const int N = in_sizes[0] / 64;
    const int E = in_sizes[1] / 2;
    const int K = (N + 255) / 256;   // segments (<= MAXK)

    auto align_up = [](size_t v) { return (v + 255) & ~(size_t)255; };
    char* ws = (char*)d_ws;
    unsigned* part    = (unsigned*)ws; ws += align_up((size_t)K * SEGCAP * 4);
    int*      segcnt  = (int*)ws;      ws += align_up((size_t)MAXK * 16 * 4);
    int*      nodeofs = (int*)ws;      ws += align_up((size_t)N * 4);
    int*      cnt     = (int*)ws;      ws += align_up((size_t)N * 4);
    int*      perm    = (int*)ws;      ws += align_up((size_t)(K * 256) * 4);
    ushort*   h1b     = (ushort*)ws;   ws += align_up((size_t)N * 64 * 2);
    ushort*   h1ob    = (ushort*)ws;   ws += align_up((size_t)N * 64 * 2);
    ushort*   h2b     = (ushort*)ws;   ws += align_up((size_t)N * 32 * 2);
    float*    al1s    = (float*)ws;    ws += align_up((size_t)N * 2 * 4);
    float*    al1d    = (float*)ws;    ws += align_up((size_t)N * 2 * 4);
    float*    al2s    = (float*)ws;    ws += align_up((size_t)N * 4);
    float*    al2d    = (float*)ws;    ws += align_up((size_t)N * 4);

    const int EB = (E + PBATCH - 1) / PBATCH;
    const int PB = (N + 63) / 64;

    hipMemsetAsync(segcnt, 0, (size_t)K * 16 * 4, stream);
    fused1<<<EB + PB, 1024, 0, stream>>>(ei, E, K, segcnt, part,
                                         x, W1, as1, ad1, h1b, al1s, al1d, N, EB);
    sortseg<<<K, 256, 0, stream>>>(segcnt, N, part, nodeofs, cnt, perm);
    aggB1<<<(N + 15) / 16, 256, 0, stream>>>(h1b, al1s, al1d, nodeofs, cnt, part,
                                             perm, b1, g1, bb1, h1ob, N);
    prep2<<<(N + 31) / 32, 256, 0, stream>>>(h1ob, W2, as2, ad2, h2b, al2s, al2d, N);
    aggB2<<<(N + 31) / 32, 256, 0, stream>>>(h2b, al2s, al2d, nodeofs, cnt, part,
                                             perm, b2, g2, bb2, Wout, bout, out, N);
}

// Round 15
// 316.585 us; speedup vs baseline: 1.0120x; 1.0120x over previous
//
#include <hip/hip_runtime.h>

#define EPS 1e-5f
#define SLOPE 0.2f
#define MAXK 512
#define SEGCAP 12288   // fixed segment stride; mean fill 8192
#define PBATCH 8192    // per partition block (1024 threads, 8 edges/thread)

__device__ __forceinline__ float leaky(float z) {
    return fmaxf(z, 0.f) + SLOPE * fminf(z, 0.f);
}
__device__ __forceinline__ ushort f2bf(float f) {
    unsigned u = __float_as_uint(f);
    u += 0x7FFFu + ((u >> 16) & 1u);
    return (ushort)(u >> 16);
}
__device__ __forceinline__ float bf2f(ushort b) {
    return __uint_as_float(((unsigned)b) << 16);
}

// -- fused stage 1: [blocks 0..EB): edge partition] ∥ [blocks EB..: prep1] --
__global__ __launch_bounds__(1024) void fused1(
    const int* __restrict__ ei, int E, int K, int* __restrict__ segcnt,
    unsigned* __restrict__ part,
    const float* __restrict__ x, const float* __restrict__ W1,
    const float* __restrict__ as1, const float* __restrict__ ad1,
    ushort* __restrict__ h1b, float* __restrict__ al_s, float* __restrict__ al_d,
    int N, int EB) {
    __shared__ float smem[4096 + 64 * 68];   // Ws | xs
    int t = threadIdx.x;
    if ((int)blockIdx.x < EB) {
        // ---------------- partition branch ----------------
        int* h   = (int*)smem;
        int* gp  = h + 512;
        int* run = h + 1024;
        for (int i = t; i < K; i += 1024) { h[i] = 0; run[i] = 0; }
        __syncthreads();
        int base = blockIdx.x * PBATCH;
        int sv[PBATCH / 1024], dv[PBATCH / 1024];
#pragma unroll
        for (int j = 0; j < PBATCH / 1024; j++) {
            int e = base + j * 1024 + t;
            sv[j] = (e < E) ? ei[e] : -1;
            dv[j] = (e < E) ? ei[E + e] : -1;
            if (dv[j] >= 0) atomicAdd(&h[dv[j] >> 8], 1);
        }
        __syncthreads();
        for (int i = t; i < K; i += 1024)
            gp[i] = h[i] ? atomicAdd(&segcnt[i * 16], h[i]) : 0;
        __syncthreads();
#pragma unroll
        for (int j = 0; j < PBATCH / 1024; j++) {
            if (dv[j] >= 0) {
                int b = dv[j] >> 8;
                int p = atomicAdd(&run[b], 1) + gp[b];
                if (p < SEGCAP)
                    part[(size_t)b * SEGCAP + p] =
                        ((unsigned)sv[j] << 8) | (unsigned)(dv[j] & 255);
            }
        }
        return;
    }
    // ---------------- prep1 branch: 64 rows/block ----------------
    float* Ws = smem;
    float (*xs)[68] = (float(*)[68])(smem + 4096);
    for (int i = t; i < 4096; i += 1024) Ws[i] = W1[i];
    int base = (blockIdx.x - EB) * 64;
    {
        int rr = t >> 4, kk = t & 15;
        int gr = base + rr;
        float4 vx = (gr < N) ? ((const float4*)x)[(size_t)gr * 16 + kk]
                             : make_float4(0.f, 0.f, 0.f, 0.f);
        *(float4*)&xs[rr][kk * 4] = vx;
    }
    __syncthreads();
    int wv = t >> 6, c = t & 63;
    int r0 = base + wv * 4;
    float acc0 = 0.f, acc1 = 0.f, acc2 = 0.f, acc3 = 0.f;
#pragma unroll
    for (int k = 0; k < 64; k += 4) {
        float4 x0 = *(const float4*)&xs[wv * 4 + 0][k];
        float4 x1 = *(const float4*)&xs[wv * 4 + 1][k];
        float4 x2 = *(const float4*)&xs[wv * 4 + 2][k];
        float4 x3 = *(const float4*)&xs[wv * 4 + 3][k];
        float w0 = Ws[(k + 0) * 64 + c];
        float w1 = Ws[(k + 1) * 64 + c];
        float w2 = Ws[(k + 2) * 64 + c];
        float w3 = Ws[(k + 3) * 64 + c];
        acc0 = fmaf(x0.x, w0, acc0); acc1 = fmaf(x1.x, w0, acc1);
        acc2 = fmaf(x2.x, w0, acc2); acc3 = fmaf(x3.x, w0, acc3);
        acc0 = fmaf(x0.y, w1, acc0); acc1 = fmaf(x1.y, w1, acc1);
        acc2 = fmaf(x2.y, w1, acc2); acc3 = fmaf(x3.y, w1, acc3);
        acc0 = fmaf(x0.z, w2, acc0); acc1 = fmaf(x1.z, w2, acc1);
        acc2 = fmaf(x2.z, w2, acc2); acc3 = fmaf(x3.z, w2, acc3);
        acc0 = fmaf(x0.w, w3, acc0); acc1 = fmaf(x1.w, w3, acc1);
        acc2 = fmaf(x2.w, w3, acc2); acc3 = fmaf(x3.w, w3, acc3);
    }
    int head = c >> 5, cc = c & 31;
    float asc = as1[head * 32 + cc], adc = ad1[head * 32 + cc];
    float vs0 = acc0 * asc, vd0 = acc0 * adc;
    float vs1 = acc1 * asc, vd1 = acc1 * adc;
    float vs2 = acc2 * asc, vd2 = acc2 * adc;
    float vs3 = acc3 * asc, vd3 = acc3 * adc;
#pragma unroll
    for (int off = 1; off < 32; off <<= 1) {
        vs0 += __shfl_xor(vs0, off); vd0 += __shfl_xor(vd0, off);
        vs1 += __shfl_xor(vs1, off); vd1 += __shfl_xor(vd1, off);
        vs2 += __shfl_xor(vs2, off); vd2 += __shfl_xor(vd2, off);
        vs3 += __shfl_xor(vs3, off); vd3 += __shfl_xor(vd3, off);
    }
    if (r0 + 0 < N) h1b[(size_t)(r0 + 0) * 64 + c] = f2bf(acc0);
    if (r0 + 1 < N) h1b[(size_t)(r0 + 1) * 64 + c] = f2bf(acc1);
    if (r0 + 2 < N) h1b[(size_t)(r0 + 2) * 64 + c] = f2bf(acc2);
    if (r0 + 3 < N) h1b[(size_t)(r0 + 3) * 64 + c] = f2bf(acc3);
    if (cc == 0) {
        if (r0 + 0 < N) { al_s[(r0 + 0) * 2 + head] = vs0; al_d[(r0 + 0) * 2 + head] = vd0; }
        if (r0 + 1 < N) { al_s[(r0 + 1) * 2 + head] = vs1; al_d[(r0 + 1) * 2 + head] = vd1; }
        if (r0 + 2 < N) { al_s[(r0 + 2) * 2 + head] = vs2; al_d[(r0 + 2) * 2 + head] = vd2; }
        if (r0 + 3 < N) { al_s[(r0 + 3) * 2 + head] = vs3; al_d[(r0 + 3) * 2 + head] = vd3; }
    }
}

// -- stage 2: per-segment LDS counting sort, 1024 threads (16 waves/block) --
__global__ __launch_bounds__(1024) void sortseg(
    const int* __restrict__ segcnt, int N,
    unsigned* __restrict__ part, int* __restrict__ nodeofs, int* __restrict__ cnt,
    int* __restrict__ perm) {
    __shared__ int h2[4096];
    __shared__ int sc[256];
    __shared__ int ex[256];
    __shared__ unsigned outb[SEGCAP];
    int b = blockIdx.x, t = threadIdx.x;
    size_t base = (size_t)b * SEGCAP;
    int sz = min(segcnt[b * 16], SEGCAP);
    for (int i = t; i < 4096; i += 1024) h2[i] = 0;
    __syncthreads();
    for (int i = t; i < sz; i += 1024) {
        unsigned code = part[base + i];
        int key = ((code & 255) << 4) | ((code >> 21) & 15);
        atomicAdd(&h2[key], 1);
    }
    __syncthreads();
    int v = 0;
    if (t < 256) {
#pragma unroll
        for (int i = 0; i < 16; i++) v += h2[t * 16 + i];
        sc[t] = v;
    }
    __syncthreads();
    for (int off = 1; off < 256; off <<= 1) {
        int xv = (t < 256 && t >= off) ? sc[t - off] : 0;
        __syncthreads();
        if (t < 256) sc[t] += xv;
        __syncthreads();
    }
    if (t < 256) {
        int exv = sc[t] - v;
        int run = exv;
#pragma unroll
        for (int i = 0; i < 16; i++) {
            int lc = h2[t * 16 + i];
            h2[t * 16 + i] = run;
            run += lc;
        }
        int n = b * 256 + t;
        if (n < N) { cnt[n] = v; nodeofs[n] = (int)(base + exv); }
    }
    __syncthreads();
    for (int i = t; i < sz; i += 1024) {
        unsigned code = part[base + i];
        int key = ((code & 255) << 4) | ((code >> 21) & 15);
        int p = atomicAdd(&h2[key], 1);
        outb[p] = code >> 8;          // src
    }
    __syncthreads();
    for (int i = t; i < sz; i += 1024) part[base + i] = outb[i];
    // ---- segment-local degree sort -> perm (lanes < 256) ----
    __syncthreads();
    if (t < 256) h2[t] = 0;
    __syncthreads();
    int n = b * 256 + t;
    int dbin = min(v, 255);
    if (t < 256 && n < N) atomicAdd(&h2[dbin], 1);
    __syncthreads();
    int hv = (t < 256) ? h2[t] : 0;
    if (t < 256) sc[t] = hv;
    __syncthreads();
    for (int off = 1; off < 256; off <<= 1) {
        int xv = (t < 256 && t >= off) ? sc[t - off] : 0;
        __syncthreads();
        if (t < 256) sc[t] += xv;
        __syncthreads();
    }
    if (t < 256) ex[t] = sc[t] - hv;
    __syncthreads();
    if (t < 256 && n < N) {
        int r = atomicAdd(&ex[dbin], 1);
        perm[b * 256 + r] = n;
    }
}

// -- layer1 aggregation: lane-cooperative 16-edge batches + LN + ELU --------
__global__ __launch_bounds__(256) void aggB1(
    const ushort* __restrict__ h1b, const float* __restrict__ als,
    const float* __restrict__ ald, const int* __restrict__ nodeofs,
    const int* __restrict__ cnt, const unsigned* __restrict__ csr,
    const int* __restrict__ perm,
    const float* __restrict__ b1, const float* __restrict__ g1,
    const float* __restrict__ bb1, ushort* __restrict__ h1out, int N) {
    int lane = threadIdx.x & 63;
    int grp = lane >> 4, q = lane & 15;
    int gbase = grp << 4;
    int idx = blockIdx.x * 16 + (threadIdx.x >> 6) * 4 + grp;
    bool valid = idx < N;
    int nc = perm[min(idx, N - 1)];
    int head = q >> 3;
    const float2* als2 = (const float2*)als;
    const float2* ald2 = (const float2*)ald;
    float2 adv = ald2[nc], asv = als2[nc];
    float ad0 = adv.x, ad1v = adv.y;
    float wsf = __expf(leaky((head ? asv.y : asv.x) + (head ? ad1v : ad0)));
    const ushort4* h4 = (const ushort4*)h1b;
    ushort4 hs = h4[(unsigned)nc * 16 + q];
    float a0 = wsf * bf2f(hs.x), a1 = wsf * bf2f(hs.y);
    float a2 = wsf * bf2f(hs.z), a3 = wsf * bf2f(hs.w);
    float l0p = 0.f, l1p = 0.f;
    int ofs = valid ? nodeofs[nc] : 0;
    int deg = valid ? cnt[nc] : 0;
    int degm1 = max(deg - 1, 0);
    int degmax = deg;              // deg uniform within 16-lane group
    degmax = max(degmax, __shfl_xor(degmax, 16));
    degmax = max(degmax, __shfl_xor(degmax, 32));
    for (int eb = 0; eb < degmax; eb += 16) {
        int j = ofs + min(eb + q, degm1);
        int sq = min((int)csr[j], N - 1);
        float2 av = als2[sq];
        float z0 = leaky(av.x + ad0);
        float z1 = leaky(av.y + ad1v);
        bool ev = (eb + q < deg);
        float w0q = ev ? __expf(z0) : 0.f;
        float w1q = ev ? __expf(z1) : 0.f;
        l0p += w0q;
        l1p += w1q;
#pragma unroll
        for (int jj = 0; jj < 16; jj++) {
            int s = __shfl(sq, gbase + jj);
            float w0 = __shfl(w0q, gbase + jj);
            float w1 = __shfl(w1q, gbase + jj);
            float w = head ? w1 : w0;
            ushort4 hv = h4[(unsigned)s * 16 + q];
            a0 = fmaf(w, bf2f(hv.x), a0);
            a1 = fmaf(w, bf2f(hv.y), a1);
            a2 = fmaf(w, bf2f(hv.z), a2);
            a3 = fmaf(w, bf2f(hv.w), a3);
        }
    }
#pragma unroll
    for (int off = 1; off < 16; off <<= 1) {
        l0p += __shfl_xor(l0p, off);
        l1p += __shfl_xor(l1p, off);
    }
    if (!valid) return;
    float l = (head ? l1p : l0p) + wsf;
    float inv = 1.f / l;
    float4 bv = ((const float4*)b1)[q];
    float v0 = a0 * inv + bv.x, v1 = a1 * inv + bv.y;
    float v2 = a2 * inv + bv.z, v3 = a3 * inv + bv.w;
    float s1 = v0 + v1 + v2 + v3;
#pragma unroll
    for (int off = 1; off < 16; off <<= 1) s1 += __shfl_xor(s1, off);
    float mu = s1 * (1.f / 64.f);
    float d0 = v0 - mu, d1 = v1 - mu, d2 = v2 - mu, d3 = v3 - mu;
    float s2v = d0 * d0 + d1 * d1 + d2 * d2 + d3 * d3;
#pragma unroll
    for (int off = 1; off < 16; off <<= 1) s2v += __shfl_xor(s2v, off);
    float rs = rsqrtf(s2v * (1.f / 64.f) + EPS);
    float4 gv = ((const float4*)g1)[q];
    float4 bbv = ((const float4*)bb1)[q];
    float y0 = d0 * rs * gv.x + bbv.x;
    float y1 = d1 * rs * gv.y + bbv.y;
    float y2 = d2 * rs * gv.z + bbv.z;
    float y3 = d3 * rs * gv.w + bbv.w;
    y0 = (y0 > 0.f) ? y0 : (__expf(y0) - 1.f);
    y1 = (y1 > 0.f) ? y1 : (__expf(y1) - 1.f);
    y2 = (y2 > 0.f) ? y2 : (__expf(y2) - 1.f);
    y3 = (y3 > 0.f) ? y3 : (__expf(y3) - 1.f);
    ((ushort4*)h1out)[(unsigned)nc * 16 + q] =
        make_ushort4(f2bf(y0), f2bf(y1), f2bf(y2), f2bf(y3));
}

// -- layer2 prep: h2 = h1out(bf16) @ W2 (bf16 out), 4 rows/lane tile --------
__global__ __launch_bounds__(256) void prep2(
    const ushort* __restrict__ h1ob, const float* __restrict__ W2,
    const float* __restrict__ as2, const float* __restrict__ ad2,
    ushort* __restrict__ h2b, float* __restrict__ al_s, float* __restrict__ al_d, int N) {
    __shared__ float Ws[64 * 32];
    __shared__ float xs[32][68];
    int t = threadIdx.x;
    for (int i = t; i < 64 * 32; i += 256) Ws[i] = W2[i];
    int base = blockIdx.x * 32;
    const ushort4* hv4 = (const ushort4*)h1ob;
    for (int i = t; i < 512; i += 256) {
        int rr = i >> 4, kk = i & 15;
        int gr = base + rr;
        ushort4 u = (gr < N) ? hv4[(unsigned)gr * 16 + kk] : make_ushort4(0, 0, 0, 0);
        xs[rr][kk * 4 + 0] = bf2f(u.x);
        xs[rr][kk * 4 + 1] = bf2f(u.y);
        xs[rr][kk * 4 + 2] = bf2f(u.z);
        xs[rr][kk * 4 + 3] = bf2f(u.w);
    }
    __syncthreads();
    int wv = t >> 6;
    int lane = t & 63;
    int half = lane >> 5, c = lane & 31;
    int rbase = wv * 8 + half * 4;
    int r0 = base + rbase;
    float acc0 = 0.f, acc1 = 0.f, acc2 = 0.f, acc3 = 0.f;
#pragma unroll
    for (int k = 0; k < 64; k += 4) {
        float4 x0 = *(const float4*)&xs[rbase + 0][k];
        float4 x1 = *(const float4*)&xs[rbase + 1][k];
        float4 x2 = *(const float4*)&xs[rbase + 2][k];
        float4 x3 = *(const float4*)&xs[rbase + 3][k];
        float w0 = Ws[(k + 0) * 32 + c];
        float w1 = Ws[(k + 1) * 32 + c];
        float w2 = Ws[(k + 2) * 32 + c];
        float w3 = Ws[(k + 3) * 32 + c];
        acc0 = fmaf(x0.x, w0, acc0); acc1 = fmaf(x1.x, w0, acc1);
        acc2 = fmaf(x2.x, w0, acc2); acc3 = fmaf(x3.x, w0, acc3);
        acc0 = fmaf(x0.y, w1, acc0); acc1 = fmaf(x1.y, w1, acc1);
        acc2 = fmaf(x2.y, w1, acc2); acc3 = fmaf(x3.y, w1, acc3);
        acc0 = fmaf(x0.z, w2, acc0); acc1 = fmaf(x1.z, w2, acc1);
        acc2 = fmaf(x2.z, w2, acc2); acc3 = fmaf(x3.z, w2, acc3);
        acc0 = fmaf(x0.w, w3, acc0); acc1 = fmaf(x1.w, w3, acc1);
        acc2 = fmaf(x2.w, w3, acc2); acc3 = fmaf(x3.w, w3, acc3);
    }
    float asc = as2[c], adc = ad2[c];
    float vs0 = acc0 * asc, vd0 = acc0 * adc;
    float vs1 = acc1 * asc, vd1 = acc1 * adc;
    float vs2 = acc2 * asc, vd2 = acc2 * adc;
    float vs3 = acc3 * asc, vd3 = acc3 * adc;
#pragma unroll
    for (int off = 1; off < 32; off <<= 1) {
        vs0 += __shfl_xor(vs0, off); vd0 += __shfl_xor(vd0, off);
        vs1 += __shfl_xor(vs1, off); vd1 += __shfl_xor(vd1, off);
        vs2 += __shfl_xor(vs2, off); vd2 += __shfl_xor(vd2, off);
        vs3 += __shfl_xor(vs3, off); vd3 += __shfl_xor(vd3, off);
    }
    if (r0 + 0 < N) h2b[(size_t)(r0 + 0) * 32 + c] = f2bf(acc0);
    if (r0 + 1 < N) h2b[(size_t)(r0 + 1) * 32 + c] = f2bf(acc1);
    if (r0 + 2 < N) h2b[(size_t)(r0 + 2) * 32 + c] = f2bf(acc2);
    if (r0 + 3 < N) h2b[(size_t)(r0 + 3) * 32 + c] = f2bf(acc3);
    if (c == 0) {
        if (r0 + 0 < N) { al_s[r0 + 0] = vs0; al_d[r0 + 0] = vd0; }
        if (r0 + 1 < N) { al_s[r0 + 1] = vs1; al_d[r0 + 1] = vd1; }
        if (r0 + 2 < N) { al_s[r0 + 2] = vs2; al_d[r0 + 2] = vd2; }
        if (r0 + 3 < N) { al_s[r0 + 3] = vs3; al_d[r0 + 3] = vd3; }
    }
}

// -- layer2 aggregation: 16-edge batches (2 edges/lane, 16 gathers in flight)
__global__ __launch_bounds__(256) void aggB2(
    const ushort* __restrict__ h2b, const float* __restrict__ als,
    const float* __restrict__ ald, const int* __restrict__ nodeofs,
    const int* __restrict__ cnt, const unsigned* __restrict__ csr,
    const int* __restrict__ perm,
    const float* __restrict__ b2, const float* __restrict__ g2,
    const float* __restrict__ bb2, const float* __restrict__ Wout,
    const float* __restrict__ bout, float* __restrict__ out, int N) {
    int lane = threadIdx.x & 63;
    int grp = lane >> 3, q = lane & 7;
    int gbase = grp << 3;
    int idx = blockIdx.x * 32 + (threadIdx.x >> 6) * 8 + grp;
    bool valid = idx < N;
    int nc = perm[min(idx, N - 1)];
    float myad = ald[nc];
    float wsf = __expf(leaky(als[nc] + myad));
    const ushort4* h4 = (const ushort4*)h2b;
    ushort4 hs = h4[(unsigned)nc * 8 + q];
    float a0 = wsf * bf2f(hs.x), a1 = wsf * bf2f(hs.y);
    float a2 = wsf * bf2f(hs.z), a3 = wsf * bf2f(hs.w);
    float lp = 0.f;
    int ofs = valid ? nodeofs[nc] : 0;
    int deg = valid ? cnt[nc] : 0;
    int degm1 = max(deg - 1, 0);
    int degmax = deg;              // uniform within 8-lane group
    degmax = max(degmax, __shfl_xor(degmax, 8));
    degmax = max(degmax, __shfl_xor(degmax, 16));
    degmax = max(degmax, __shfl_xor(degmax, 32));
    for (int eb = 0; eb < degmax; eb += 16) {
        int j0 = ofs + min(eb + q, degm1);
        int j1 = ofs + min(eb + 8 + q, degm1);
        int sq0 = min((int)csr[j0], N - 1);
        int sq1 = min((int)csr[j1], N - 1);
        float z0 = leaky(als[sq0] + myad);
        float z1 = leaky(als[sq1] + myad);
        float wq0 = (eb + q < deg) ? __expf(z0) : 0.f;
        float wq1 = (eb + 8 + q < deg) ? __expf(z1) : 0.f;
        lp += wq0 + wq1;
#pragma unroll
        for (int jj = 0; jj < 8; jj++) {
            int s0 = __shfl(sq0, gbase + jj);
            float w0 = __shfl(wq0, gbase + jj);
            int s1 = __shfl(sq1, gbase + jj);
            float w1 = __shfl(wq1, gbase + jj);
            ushort4 hv0 = h4[(unsigned)s0 * 8 + q];
            ushort4 hv1 = h4[(unsigned)s1 * 8 + q];
            a0 = fmaf(w0, bf2f(hv0.x), a0);
            a1 = fmaf(w0, bf2f(hv0.y), a1);
            a2 = fmaf(w0, bf2f(hv0.z), a2);
            a3 = fmaf(w0, bf2f(hv0.w), a3);
            a0 = fmaf(w1, bf2f(hv1.x), a0);
            a1 = fmaf(w1, bf2f(hv1.y), a1);
            a2 = fmaf(w1, bf2f(hv1.z), a2);
            a3 = fmaf(w1, bf2f(hv1.w), a3);
        }
    }
#pragma unroll
    for (int off = 1; off < 8; off <<= 1) lp += __shfl_xor(lp, off);
    if (!valid) return;
    float l = lp + wsf;
    float inv = 1.f / l;
    float4 bv = ((const float4*)b2)[q];
    float v0 = a0 * inv + bv.x, v1 = a1 * inv + bv.y;
    float v2 = a2 * inv + bv.z, v3 = a3 * inv + bv.w;
    float s1 = v0 + v1 + v2 + v3;
#pragma unroll
    for (int off = 1; off < 8; off <<= 1) s1 += __shfl_xor(s1, off);
    float mu = s1 * (1.f / 32.f);
    float d0 = v0 - mu, d1 = v1 - mu, d2 = v2 - mu, d3 = v3 - mu;
    float s2v = d0 * d0 + d1 * d1 + d2 * d2 + d3 * d3;
#pragma unroll
    for (int off = 1; off < 8; off <<= 1) s2v += __shfl_xor(s2v, off);
    float rs = rsqrtf(s2v * (1.f / 32.f) + EPS);
    float4 gv = ((const float4*)g2)[q];
    float4 bbv = ((const float4*)bb2)[q];
    float y0 = d0 * rs * gv.x + bbv.x;
    float y1 = d1 * rs * gv.y + bbv.y;
    float y2 = d2 * rs * gv.z + bbv.z;
    float y3 = d3 * rs * gv.w + bbv.w;
    y0 = (y0 > 0.f) ? y0 : (__expf(y0) - 1.f);
    y1 = (y1 > 0.f) ? y1 : (__expf(y1) - 1.f);
    y2 = (y2 > 0.f) ? y2 : (__expf(y2) - 1.f);
    y3 = (y3 > 0.f) ? y3 : (__expf(y3) - 1.f);
    float4 wo = ((const float4*)Wout)[q];
    float p = y0 * wo.x + y1 * wo.y + y2 * wo.z + y3 * wo.w;
#pragma unroll
    for (int off = 1; off < 8; off <<= 1) p += __shfl_xor(p, off);
    if (q == 0) out[nc] = p + bout[0];
}

extern "C" void kernel_launch(void* const* d_in, const int* in_sizes, int n_in,
                              void* d_out, int out_size, void* d_ws, size_t ws_size,
                              hipStream_t stream) {
    const float* x    = (const float*)d_in[0];
    const int*   ei   = (const int*)d_in[1];
    const float* W1   = (const float*)d_in[2];
    const float* as1  = (const float*)d_in[3];
    const float* ad1  = (const float*)d_in[4];
    const float* b1   = (const float*)d_in[5];
    const float* g1   = (const float*)d_in[6];
    const float* bb1  = (const float*)d_in[7];
    const float* W2   = (const float*)d_in[8];
    const float* as2  = (const float*)d_in[9];
    const float* ad2  = (const float*)d_in[10];
    const float* b2   = (const float*)d_in[11];
    const float* g2   = (const float*)d_in[12];
    const float* bb2  = (const float*)d_in[13];
    const float* Wout = (const float*)d_in[14];
    const float* bout = (const float*)d_in[15];
    float* out = (float*)d_out;

    const int N = in_sizes[0] / 64;
    const int E = in_sizes[1] / 2;
    const int K = (N + 255) / 256;   // segments (<= MAXK)

    auto align_up = [](size_t v) { return (v + 255) & ~(size_t)255; };
    char* ws = (char*)d_ws;
    unsigned* part    = (unsigned*)ws; ws += align_up((size_t)K * SEGCAP * 4);
    int*      segcnt  = (int*)ws;      ws += align_up((size_t)MAXK * 16 * 4);
    int*      nodeofs = (int*)ws;      ws += align_up((size_t)N * 4);
    int*      cnt     = (int*)ws;      ws += align_up((size_t)N * 4);
    int*      perm    = (int*)ws;      ws += align_up((size_t)(K * 256) * 4);
    ushort*   h1b     = (ushort*)ws;   ws += align_up((size_t)N * 64 * 2);
    ushort*   h1ob    = (ushort*)ws;   ws += align_up((size_t)N * 64 * 2);
    ushort*   h2b     = (ushort*)ws;   ws += align_up((size_t)N * 32 * 2);
    float*    al1s    = (float*)ws;    ws += align_up((size_t)N * 2 * 4);
    float*    al1d    = (float*)ws;    ws += align_up((size_t)N * 2 * 4);
    float*    al2s    = (float*)ws;    ws += align_up((size_t)N * 4);
    float*    al2d    = (float*)ws;    ws += align_up((size_t)N * 4);

    const int EB = (E + PBATCH - 1) / PBATCH;
    const int PB = (N + 63) / 64;

    hipMemsetAsync(segcnt, 0, (size_t)K * 16 * 4, stream);
    fused1<<<EB + PB, 1024, 0, stream>>>(ei, E, K, segcnt, part,
                                         x, W1, as1, ad1, h1b, al1s, al1d, N, EB);
    sortseg<<<K, 1024, 0, stream>>>(segcnt, N, part, nodeofs, cnt, perm);
    aggB1<<<(N + 15) / 16, 256, 0, stream>>>(h1b, al1s, al1d, nodeofs, cnt, part,
                                             perm, b1, g1, bb1, h1ob, N);
    prep2<<<(N + 31) / 32, 256, 0, stream>>>(h1ob, W2, as2, ad2, h2b, al2s, al2d, N);
    aggB2<<<(N + 31) / 32, 256, 0, stream>>>(h2b, al2s, al2d, nodeofs, cnt, part,
                                             perm, b2, g2, bb2, Wout, bout, out, N);
}